// Round 3
// baseline (610.970 us; speedup 1.0000x reference)
//
#include <hip/hip_runtime.h>

#define NWIN 2048
#define NTOK 64
#define CDIM 256
#define NH 8
#define HD 32
#define QSCALE 0.17677669529663689f   // 32^-0.5

typedef __bf16 bf16x8 __attribute__((ext_vector_type(8)));
typedef float  f32x4  __attribute__((ext_vector_type(4)));
typedef unsigned short u16x8 __attribute__((ext_vector_type(8)));

__device__ __forceinline__ unsigned short f2bf(float f) {
    union { float f; unsigned u; } v; v.f = f;
    unsigned r = v.u + 0x7FFFu + ((v.u >> 16) & 1u);   // RNE
    return (unsigned short)(r >> 16);
}
__device__ __forceinline__ bf16x8 ld16(const unsigned short* p) {
    return *(const bf16x8*)p;
}

// ---- precast: weights fp32->bf16; bias_table -> relbT[h][col][row] fp32 ----
__global__ void precast_kernel(const float* __restrict__ wq, const float* __restrict__ wp,
                               const float* __restrict__ bt,
                               unsigned short* __restrict__ wqb, unsigned short* __restrict__ wpb,
                               float* __restrict__ relbT) {
    int i = blockIdx.x * 256 + threadIdx.x;
    if (i < 196608) {
        wqb[i] = f2bf(wq[i]);
    } else if (i < 262144) {
        wpb[i - 196608] = f2bf(wp[i - 196608]);
    } else if (i < 294912) {
        int j = i - 262144;            // h*4096 + c*64 + r  (c = key col, r = query row)
        int h = j >> 12;
        int c = (j >> 6) & 63;
        int r = j & 63;
        int yi = r >> 3, xi = r & 7, yj = c >> 3, xj = c & 7;
        int idx = (yi - yj + 7) * 15 + (xi - xj + 7);
        relbT[j] = bt[idx * NH + h];
    }
}

// K1: fused qkv + attention. 256 thr / 4 waves, wave w -> heads {w, w+4}.
// LDS 48KB -> 3 blocks/CU = 12 waves/CU. ONE barrier (x staging).
// attn_out (bf16) staged into the FIRST 32KB of window b's OWN 64KB d_out
// region (short offset b*2*NTOK*CDIM) -- proj block b reads only its own region.
__global__ __launch_bounds__(256, 3)
void win_attn_kernel(const float* __restrict__ x, const float* __restrict__ mask,
                     const float* __restrict__ bqkv,
                     const unsigned short* __restrict__ wq,
                     const float* __restrict__ relbT,
                     unsigned short* __restrict__ aout) {
    // x frags: 32 frags (mt,ks) x 512 shorts = 16384; per-wave scratch 2048 shorts x 4
    __shared__ __align__(16) unsigned short sm[24576];   // 49152 B

    const int b    = blockIdx.x;
    const int tid  = threadIdx.x;
    const int wv   = tid >> 6;
    const int lane = tid & 63;
    const int lm   = lane & 15;
    const int quad = lane >> 4;
    unsigned short* scr = sm + 16384 + wv * 2048;        // wave-private 4KB
    const f32x4 fzero = {0.f, 0.f, 0.f, 0.f};

    // ---------- Phase 0: stage x window as bf16 A-frags (frag-major) ----------
    {
        const int row = tid >> 2;                 // 64 rows, 4 threads/row
        const int mt = row >> 4, lr = row & 15;
        const float* gx = x + ((size_t)b * NTOK + row) * CDIM;
        #pragma unroll
        for (int kk = 0; kk < 2; ++kk) {
            const int ks = (tid & 3) * 2 + kk;
            #pragma unroll
            for (int q = 0; q < 4; ++q) {
                float4 v0 = *(const float4*)(gx + ks * 32 + q * 8);
                float4 v1 = *(const float4*)(gx + ks * 32 + q * 8 + 4);
                u16x8 u;
                u[0] = f2bf(v0.x); u[1] = f2bf(v0.y); u[2] = f2bf(v0.z); u[3] = f2bf(v0.w);
                u[4] = f2bf(v1.x); u[5] = f2bf(v1.y); u[6] = f2bf(v1.z); u[7] = f2bf(v1.w);
                *(u16x8*)(sm + (mt * 8 + ks) * 512 + (lr + 16 * q) * 8) = u;
            }
        }
    }
    __syncthreads();   // the ONLY barrier in this kernel

    const float* maskb = mask + (size_t)b * (NTOK * NTOK);

    for (int hi = 0; hi < 2; ++hi) {
        const int h = wv + hi * 4;

        // biases for this head (per-lane, feature = tile*16 + lm)
        const float bq0 = bqkv[h * HD + lm],            bq1 = bqkv[h * HD + 16 + lm];
        const float bk0 = bqkv[CDIM + h * HD + lm],     bk1 = bqkv[CDIM + h * HD + 16 + lm];
        const float bv0 = bqkv[2 * CDIM + h * HD + lm], bv1 = bqkv[2 * CDIM + h * HD + 16 + lm];

        // ---------- pass A: q,k accs ----------
        f32x4 aq[2][4], ak[2][4];
        #pragma unroll
        for (int t = 0; t < 2; ++t)
            #pragma unroll
            for (int mt = 0; mt < 4; ++mt) { aq[t][mt] = fzero; ak[t][mt] = fzero; }

        #pragma unroll
        for (int ks = 0; ks < 8; ++ks) {
            bf16x8 bfq0 = ld16(wq + ((h * HD + lm) * CDIM) + ks * 32 + quad * 8);
            bf16x8 bfq1 = ld16(wq + ((h * HD + 16 + lm) * CDIM) + ks * 32 + quad * 8);
            bf16x8 bfk0 = ld16(wq + ((CDIM + h * HD + lm) * CDIM) + ks * 32 + quad * 8);
            bf16x8 bfk1 = ld16(wq + ((CDIM + h * HD + 16 + lm) * CDIM) + ks * 32 + quad * 8);
            #pragma unroll
            for (int mt = 0; mt < 4; ++mt) {
                bf16x8 afr = ld16(sm + (mt * 8 + ks) * 512 + lane * 8);
                aq[0][mt] = __builtin_amdgcn_mfma_f32_16x16x32_bf16(afr, bfq0, aq[0][mt], 0, 0, 0);
                aq[1][mt] = __builtin_amdgcn_mfma_f32_16x16x32_bf16(afr, bfq1, aq[1][mt], 0, 0, 0);
                ak[0][mt] = __builtin_amdgcn_mfma_f32_16x16x32_bf16(afr, bfk0, ak[0][mt], 0, 0, 0);
                ak[1][mt] = __builtin_amdgcn_mfma_f32_16x16x32_bf16(afr, bfk1, ak[1][mt], 0, 0, 0);
            }
        }

        // ---------- K transpose: C-layout -> B-frags in scratch -> regs ----------
        // B-frag jt(=mt): lane' = (tok&15) + 16*(feat>>3), j = feat&7
        #pragma unroll
        for (int mt = 0; mt < 4; ++mt)
            #pragma unroll
            for (int kt = 0; kt < 2; ++kt)
                #pragma unroll
                for (int reg = 0; reg < 4; ++reg) {
                    float val = ak[kt][mt][reg] + (kt ? bk1 : bk0);
                    int lp = quad * 4 + reg + 16 * (kt * 2 + (lm >> 3));
                    scr[mt * 512 + lp * 8 + (lm & 7)] = f2bf(val);
                }
        bf16x8 kf[4];
        #pragma unroll
        for (int jt = 0; jt < 4; ++jt) kf[jt] = ld16(scr + jt * 512 + lane * 8);

        // ---------- Q transpose: C-layout -> A-frags in scratch -> regs ----------
        #pragma unroll
        for (int mt = 0; mt < 4; ++mt)
            #pragma unroll
            for (int qt = 0; qt < 2; ++qt)
                #pragma unroll
                for (int reg = 0; reg < 4; ++reg) {
                    float val = (aq[qt][mt][reg] + (qt ? bq1 : bq0)) * QSCALE;
                    int lp = quad * 4 + reg + 16 * (qt * 2 + (lm >> 3));
                    scr[mt * 512 + lp * 8 + (lm & 7)] = f2bf(val);
                }
        bf16x8 qa[4];
        #pragma unroll
        for (int mt = 0; mt < 4; ++mt) qa[mt] = ld16(scr + mt * 512 + lane * 8);

        // ---------- pass B: v accs ----------
        f32x4 av[2][4];
        #pragma unroll
        for (int t = 0; t < 2; ++t)
            #pragma unroll
            for (int mt = 0; mt < 4; ++mt) av[t][mt] = fzero;
        #pragma unroll
        for (int ks = 0; ks < 8; ++ks) {
            bf16x8 bfv0 = ld16(wq + ((2 * CDIM + h * HD + lm) * CDIM) + ks * 32 + quad * 8);
            bf16x8 bfv1 = ld16(wq + ((2 * CDIM + h * HD + 16 + lm) * CDIM) + ks * 32 + quad * 8);
            #pragma unroll
            for (int mt = 0; mt < 4; ++mt) {
                bf16x8 afr = ld16(sm + (mt * 8 + ks) * 512 + lane * 8);
                av[0][mt] = __builtin_amdgcn_mfma_f32_16x16x32_bf16(afr, bfv0, av[0][mt], 0, 0, 0);
                av[1][mt] = __builtin_amdgcn_mfma_f32_16x16x32_bf16(afr, bfv1, av[1][mt], 0, 0, 0);
            }
        }

        // ---------- V transpose: C-layout -> B-frags (n=d, k=tok) -> regs ----------
        // frag (nt=vt, kk=mt>>1): lane' = lm + 16*((mt&1)*2 + ((quad*4+reg)>>3)), j=(quad*4+reg)&7
        #pragma unroll
        for (int mt = 0; mt < 4; ++mt)
            #pragma unroll
            for (int vt = 0; vt < 2; ++vt)
                #pragma unroll
                for (int reg = 0; reg < 4; ++reg) {
                    float val = av[vt][mt][reg] + (vt ? bv1 : bv0);
                    int tk = quad * 4 + reg;
                    int lp = lm + 16 * ((mt & 1) * 2 + (tk >> 3));
                    scr[(vt * 2 + (mt >> 1)) * 512 + lp * 8 + (tk & 7)] = f2bf(val);
                }
        bf16x8 vf[2][2];
        #pragma unroll
        for (int vt = 0; vt < 2; ++vt)
            #pragma unroll
            for (int kk = 0; kk < 2; ++kk)
                vf[vt][kk] = ld16(scr + (vt * 2 + kk) * 512 + lane * 8);

        // ---------- attention ----------
        const float* relh = relbT + h * (NTOK * NTOK);
        unsigned short* ao = aout + (size_t)b * (2 * NTOK * CDIM) + h * HD;   // FIXED offset

        float mnxt[16];
        #pragma unroll
        for (int jt = 0; jt < 4; ++jt)
            #pragma unroll
            for (int reg = 0; reg < 4; ++reg)
                mnxt[jt * 4 + reg] = maskb[(quad * 4 + reg) * 64 + jt * 16 + lm];

        #pragma unroll
        for (int rc = 0; rc < 4; ++rc) {
            const int m0 = rc * 16;
            float mcur[16];
            #pragma unroll
            for (int i = 0; i < 16; ++i) mcur[i] = mnxt[i];
            if (rc < 3) {
                #pragma unroll
                for (int jt = 0; jt < 4; ++jt)
                    #pragma unroll
                    for (int reg = 0; reg < 4; ++reg)
                        mnxt[jt * 4 + reg] = maskb[(m0 + 16 + quad * 4 + reg) * 64 + jt * 16 + lm];
            }

            float4 rb[4];
            #pragma unroll
            for (int jt = 0; jt < 4; ++jt)
                rb[jt] = *(const float4*)(relh + (jt * 16 + lm) * 64 + m0 + quad * 4);

            f32x4 s[4];
            #pragma unroll
            for (int jt = 0; jt < 4; ++jt)
                s[jt] = __builtin_amdgcn_mfma_f32_16x16x32_bf16(qa[rc], kf[jt], fzero, 0, 0, 0);

            #pragma unroll
            for (int jt = 0; jt < 4; ++jt) {
                float rbv[4] = { rb[jt].x, rb[jt].y, rb[jt].z, rb[jt].w };
                #pragma unroll
                for (int reg = 0; reg < 4; ++reg)
                    s[jt][reg] += rbv[reg] + mcur[jt * 4 + reg];
            }

            float inv[4];
            float p[4][4];
            #pragma unroll
            for (int reg = 0; reg < 4; ++reg) {
                float m_ = fmaxf(fmaxf(s[0][reg], s[1][reg]), fmaxf(s[2][reg], s[3][reg]));
                #pragma unroll
                for (int off = 1; off < 16; off <<= 1)
                    m_ = fmaxf(m_, __shfl_xor(m_, off, 64));
                #pragma unroll
                for (int jt = 0; jt < 4; ++jt)
                    p[jt][reg] = __expf(s[jt][reg] - m_);
                float s_ = (p[0][reg] + p[1][reg]) + (p[2][reg] + p[3][reg]);
                #pragma unroll
                for (int off = 1; off < 16; off <<= 1)
                    s_ += __shfl_xor(s_, off, 64);
                inv[reg] = __builtin_amdgcn_rcpf(s_);
            }

            // P: C-layout -> A-frags in scratch (1KB) -> regs
            #pragma unroll
            for (int jt = 0; jt < 4; ++jt)
                #pragma unroll
                for (int reg = 0; reg < 4; ++reg) {
                    int lp = quad * 4 + reg + 16 * ((jt & 1) * 2 + (lm >> 3));
                    scr[(jt >> 1) * 512 + lp * 8 + (lm & 7)] = f2bf(p[jt][reg]);
                }
            bf16x8 pa0 = ld16(scr + lane * 8);
            bf16x8 pa1 = ld16(scr + 512 + lane * 8);

            #pragma unroll
            for (int nt = 0; nt < 2; ++nt) {
                f32x4 o = __builtin_amdgcn_mfma_f32_16x16x32_bf16(pa0, vf[nt][0], fzero, 0, 0, 0);
                o = __builtin_amdgcn_mfma_f32_16x16x32_bf16(pa1, vf[nt][1], o, 0, 0, 0);
                #pragma unroll
                for (int reg = 0; reg < 4; ++reg) {
                    int r = m0 + quad * 4 + reg;
                    ao[(size_t)r * CDIM + nt * 16 + lm] = f2bf(o[reg] * inv[reg]);
                }
            }
        }
    }
}

// K2: out = attn @ wp^T + bp. Block b reads its own staged 32KB (bf16, first
// half of its 64KB region) into LDS, barriers, then overwrites its full 64KB
// region with fp32. No cross-block data flow.
__global__ __launch_bounds__(256, 4)
void proj_kernel(const unsigned short* __restrict__ wp, const float* __restrict__ bp,
                 float* out) {
    __shared__ __align__(16) unsigned short sa[16896];   // 64 x 264 (padded) bf16

    const int b    = blockIdx.x;
    const int tid  = threadIdx.x;
    const int wv   = tid >> 6;
    const int lane = tid & 63;
    const int lm   = lane & 15;
    const int quad = lane >> 4;
    const f32x4 fzero = {0.f, 0.f, 0.f, 0.f};

    const unsigned short* src = (const unsigned short*)out + (size_t)b * (2 * NTOK * CDIM);
    {
        const int col = (tid & 31) * 8;          // linear global reads, padded LDS stores
        #pragma unroll
        for (int i = 0; i < 8; ++i) {
            const int row = i * 8 + (tid >> 5);
            bf16x8 v = *(const bf16x8*)(src + row * CDIM + col);
            *(bf16x8*)(sa + row * 264 + col) = v;
        }
    }
    __syncthreads();

    const int n0 = wv * 64;
    f32x4 acc[4][4];
    #pragma unroll
    for (int mt = 0; mt < 4; ++mt)
        #pragma unroll
        for (int nt = 0; nt < 4; ++nt) acc[mt][nt] = fzero;

    #pragma unroll
    for (int ks = 0; ks < 8; ++ks) {
        bf16x8 bfr[4];
        #pragma unroll
        for (int nt = 0; nt < 4; ++nt)
            bfr[nt] = ld16(wp + (n0 + nt * 16 + lm) * CDIM + ks * 32 + quad * 8);
        bf16x8 afr[4];
        #pragma unroll
        for (int mt = 0; mt < 4; ++mt)
            afr[mt] = ld16(sa + (mt * 16 + lm) * 264 + ks * 32 + quad * 8);
        #pragma unroll
        for (int mt = 0; mt < 4; ++mt)
            #pragma unroll
            for (int nt = 0; nt < 4; ++nt)
                acc[mt][nt] = __builtin_amdgcn_mfma_f32_16x16x32_bf16(afr[mt], bfr[nt], acc[mt][nt], 0, 0, 0);
    }

    float bpv[4];
    #pragma unroll
    for (int nt = 0; nt < 4; ++nt) bpv[nt] = bp[n0 + nt * 16 + lm];

    #pragma unroll
    for (int mt = 0; mt < 4; ++mt)
        #pragma unroll
        for (int nt = 0; nt < 4; ++nt)
            #pragma unroll
            for (int reg = 0; reg < 4; ++reg) {
                int r = mt * 16 + quad * 4 + reg;
                out[((size_t)b * NTOK + r) * CDIM + n0 + nt * 16 + lm] = acc[mt][nt][reg] + bpv[nt];
            }
}

extern "C" void kernel_launch(void* const* d_in, const int* in_sizes, int n_in,
                              void* d_out, int out_size, void* d_ws, size_t ws_size,
                              hipStream_t stream) {
    const float* x    = (const float*)d_in[0];
    const float* mask = (const float*)d_in[1];
    const float* wq   = (const float*)d_in[2];
    const float* bq   = (const float*)d_in[3];
    const float* wp   = (const float*)d_in[4];
    const float* bp   = (const float*)d_in[5];
    const float* bt   = (const float*)d_in[6];

    unsigned short* wqb   = (unsigned short*)d_ws;              // 768x256 bf16
    unsigned short* wpb   = wqb + 196608;                        // 256x256 bf16
    float*          relbT = (float*)((char*)d_ws + 524288);     // 8x64x64 fp32 (h, col, row)

    precast_kernel<<<1152, 256, 0, stream>>>(wq, wp, bt, wqb, wpb, relbT);
    win_attn_kernel<<<NWIN, 256, 0, stream>>>(x, mask, bq, wqb, relbT,
                                              (unsigned short*)d_out);
    proj_kernel<<<NWIN, 256, 0, stream>>>(wpb, bp, (float*)d_out);
}